// Round 7
// baseline (659.401 us; speedup 1.0000x reference)
//
#include <hip/hip_runtime.h>
#include <cstddef>

// RelPositionMultiHeadAttention — round 7: identical resubmission of round-5
// source (rounds 5 and 6 both hit GPUAcquisitionTimeout; never benched).
// Changes vs round 4 (flash was latency-bound at 1 block/CU, MfmaUtil 5%):
//  * mask folded into bdS (gemm_bd_shifted epilogue stores NEG_INF/SCALE at
//    masked slots) — no mask reads in flash.
//  * flash: bd tile staged to LDS via coalesced global_load_lds; acc_s init
//    reads LDS, zero scalar global loads.
//  * flash re-shaped: 64-row t-tile, 256 thr (4 waves), 50 KB LDS -> ~3
//    blocks/CU, grid 512 blocks (was 256x512thr = 1 block/CU).
//  * q/k/v/p projections merged into one z-indexed dispatch (1024 blocks).

#define B_ 4
#define T_ 1024
#define D_ 1024
#define H_ 8
#define DK_ 128
#define P_ 2047
#define SCALE_F 0.08838834764831845f
#define NEG_INF_F (-10000.0f)

typedef unsigned short ushort_t;
typedef __attribute__((ext_vector_type(8))) short short8;
typedef __attribute__((ext_vector_type(8))) unsigned short ushortx8;
typedef __attribute__((ext_vector_type(4))) float f32x4;

__device__ __forceinline__ ushort_t f2bf(float f) {
    unsigned u = __float_as_uint(f);
    unsigned r = (u + 0x7FFFu + ((u >> 16) & 1u)) >> 16;   // RNE
    return (ushort_t)r;
}
__device__ __forceinline__ float bf2f(ushort_t b) {
    return __uint_as_float(((unsigned)b) << 16);
}

__device__ __forceinline__ void gload_lds16(const ushort_t* src, ushort_t* dst) {
    __builtin_amdgcn_global_load_lds(
        (const __attribute__((address_space(1))) unsigned int*)src,
        (__attribute__((address_space(3))) unsigned int*)dst, 16, 0, 0);
}

// ---------------- 256-thread GEMM building blocks (proven, rounds 3-4) ------
__device__ __forceinline__ void stage128x64(const ushort_t* __restrict__ g, int ldg,
                                            int rowBase, int rowMax,
                                            ushort_t* lds, int k0)
{
    const int tid = threadIdx.x;
    const int w = tid >> 6;
    #pragma unroll
    for (int u = 0; u < 4; ++u) {
        int e = tid * 8 + u * 2048;
        int row = e >> 6, col = e & 63;
        int gr = rowBase + row; if (gr > rowMax - 1) gr = rowMax - 1;
        const ushort_t* src = g + (size_t)gr * ldg + k0 + col;
        ushort_t* dst = lds + w * 512 + u * 2048;   // wave-uniform; HW adds lane*16B
        gload_lds16(src, dst);
    }
}

__device__ __forceinline__ void mma128(const ushort_t* As, const ushort_t* Bs, f32x4 acc[4][4])
{
    const int lane = threadIdx.x & 63;
    const int w = threadIdx.x >> 6;
    const int wr = (w >> 1) * 64, wc = (w & 1) * 64;
    const int lr = lane & 15, lk = (lane >> 4) * 8;
    #pragma unroll
    for (int kk = 0; kk < 2; ++kk) {
        short8 a[4], b[4];
        #pragma unroll
        for (int i = 0; i < 4; ++i)
            a[i] = *(const short8*)&As[(size_t)(wr + i * 16 + lr) * 64 + kk * 32 + lk];
        #pragma unroll
        for (int j = 0; j < 4; ++j)
            b[j] = *(const short8*)&Bs[(size_t)(wc + j * 16 + lr) * 64 + kk * 32 + lk];
        #pragma unroll
        for (int i = 0; i < 4; ++i)
            #pragma unroll
            for (int j = 0; j < 4; ++j)
                acc[i][j] = __builtin_amdgcn_mfma_f32_16x16x32_bf16(a[i], b[j], acc[i][j], 0, 0, 0);
    }
}

#define ACC_DECL f32x4 acc[4][4]; \
    _Pragma("unroll") for (int i_ = 0; i_ < 4; ++i_) \
    _Pragma("unroll") for (int j_ = 0; j_ < 4; ++j_) \
    _Pragma("unroll") for (int r_ = 0; r_ < 4; ++r_) acc[i_][j_][r_] = 0.f;

#define EPI_COORDS \
    const int lane = threadIdx.x & 63; \
    const int w = threadIdx.x >> 6; \
    const int wr = (w >> 1) * 64, wc = (w & 1) * 64; \
    const int lcol = lane & 15, lrow4 = (lane >> 4) * 4;

// ---------------------------------------------------------------------------
// Combined q/k/v/p projection: z = 0:q(dual out +pbu/pbv) 1:k 2:v 3:p(M=2047).
// grid (8, 32, 4); z==3 uses only y<16.
// ---------------------------------------------------------------------------
__global__ __launch_bounds__(256)
void gemm_qkvp(const ushort_t* __restrict__ qA, const ushort_t* __restrict__ kA,
               const ushort_t* __restrict__ vA, const ushort_t* __restrict__ pA,
               const ushort_t* __restrict__ WqT, const ushort_t* __restrict__ WkT,
               const ushort_t* __restrict__ WvT, const ushort_t* __restrict__ WpT,
               const float* __restrict__ bq, const float* __restrict__ bk,
               const float* __restrict__ bv,
               ushort_t* __restrict__ quO, ushort_t* __restrict__ qvO,
               ushort_t* __restrict__ kO, ushort_t* __restrict__ vO,
               ushort_t* __restrict__ pO,
               const float* __restrict__ pbu, const float* __restrict__ pbv)
{
    const int z = blockIdx.z;
    if (z == 3 && blockIdx.y >= 16) return;
    const ushort_t* A  = z == 0 ? qA  : z == 1 ? kA  : z == 2 ? vA  : pA;
    const ushort_t* Bt = z == 0 ? WqT : z == 1 ? WkT : z == 2 ? WvT : WpT;
    const int M = (z == 3) ? P_ : B_ * T_;

    __shared__ ushort_t As[128 * 64], Bs[128 * 64];
    const int n0 = blockIdx.x * 128, m0 = blockIdx.y * 128;
    ACC_DECL;
    for (int k0 = 0; k0 < 1024; k0 += 64) {
        stage128x64(A, 1024, m0, M, As, k0);
        stage128x64(Bt, 1024, n0, 1024, Bs, k0);
        __syncthreads();
        mma128(As, Bs, acc);
        __syncthreads();
    }
    EPI_COORDS;
    #pragma unroll
    for (int i = 0; i < 4; ++i)
        #pragma unroll
        for (int j = 0; j < 4; ++j)
            #pragma unroll
            for (int r = 0; r < 4; ++r) {
                int m = m0 + wr + i * 16 + lrow4 + r;
                int n = n0 + wc + j * 16 + lcol;
                if (m >= M) continue;
                float v = acc[i][j][r];
                size_t o = (size_t)m * 1024 + n;
                if (z == 0) {
                    v += bq[n];
                    quO[o] = f2bf(v + pbu[n]);
                    qvO[o] = f2bf(v + pbv[n]);
                } else if (z == 1) kO[o] = f2bf(v + bk[n]);
                else if (z == 2)  vO[o] = f2bf(v + bv[n]);
                else              pO[o] = f2bf(v);
            }
}

// ---------------------------------------------------------------------------
// Output projection: out_f32[M,1024] = ctx@WoT^T + bo
// ---------------------------------------------------------------------------
__global__ __launch_bounds__(256)
void gemm_out(const ushort_t* __restrict__ A, const ushort_t* __restrict__ Bt,
              const float* __restrict__ bias, float* __restrict__ out, int M)
{
    __shared__ ushort_t As[128 * 64], Bs[128 * 64];
    const int n0 = blockIdx.x * 128, m0 = blockIdx.y * 128;
    ACC_DECL;
    for (int k0 = 0; k0 < 1024; k0 += 64) {
        stage128x64(A, 1024, m0, M, As, k0);
        stage128x64(Bt, 1024, n0, 1024, Bs, k0);
        __syncthreads();
        mma128(As, Bs, acc);
        __syncthreads();
    }
    EPI_COORDS;
    #pragma unroll
    for (int i = 0; i < 4; ++i)
        #pragma unroll
        for (int j = 0; j < 4; ++j)
            #pragma unroll
            for (int r = 0; r < 4; ++r) {
                int m = m0 + wr + i * 16 + lrow4 + r;
                int n = n0 + wc + j * 16 + lcol;
                if (m >= M) continue;
                out[(size_t)m * 1024 + n] = acc[i][j][r] + bias[n];
            }
}

// ---------------------------------------------------------------------------
// bdS[lb,h,t,s] = mask[b,t,s] ? NEG_INF/SCALE : qv[b,t,h*128+:].p[s+1023-t, h*128+:]
// Dense GEMM over j; rel-shift + mask fold in the store predicate.
// grid (16, 8, nb*H)
// ---------------------------------------------------------------------------
__global__ __launch_bounds__(256)
void gemm_bd_shifted(const ushort_t* __restrict__ qv, const ushort_t* __restrict__ p,
                     const unsigned char* __restrict__ mask,
                     ushort_t* __restrict__ bdS, int b0)
{
    __shared__ ushort_t As[128 * 64], Bs[128 * 64];
    const int j0 = blockIdx.x * 128, t0 = blockIdx.y * 128;
    const int lb = blockIdx.z >> 3, h = blockIdx.z & 7;
    const int b = b0 + lb;
    const ushort_t* Ab = qv + (size_t)b * T_ * D_ + h * DK_;
    const ushort_t* Bb = p + h * DK_;
    ACC_DECL;
    for (int k0 = 0; k0 < DK_; k0 += 64) {
        stage128x64(Ab, D_, t0, T_, As, k0);
        stage128x64(Bb, D_, j0, P_, Bs, k0);     // row 2047 clamped (never stored)
        __syncthreads();
        mma128(As, Bs, acc);
        __syncthreads();
    }
    EPI_COORDS;
    const ushort_t MASKED_BF = f2bf(NEG_INF_F / SCALE_F);
    ushort_t* ob = bdS + (size_t)(lb * H_ + h) * T_ * T_;
    const unsigned char* mB = mask + (size_t)b * T_ * T_;
    #pragma unroll
    for (int i = 0; i < 4; ++i)
        #pragma unroll
        for (int j = 0; j < 4; ++j)
            #pragma unroll
            for (int r = 0; r < 4; ++r) {
                int t = t0 + wr + i * 16 + lrow4 + r;
                int jj = j0 + wc + j * 16 + lcol;
                int s = jj + t - (T_ - 1);
                if (s >= 0 && s < T_) {
                    unsigned char mk = mB[(size_t)t * T_ + s];
                    ob[(size_t)t * T_ + s] = mk ? MASKED_BF : f2bf(acc[i][j][r]);
                }
            }
}

// ---------------------------------------------------------------------------
// 256-thread swizzled stager: LDS [128 rows][64 cols] bf16 linear dest; global
// source pre-swizzled: LDS slot (row, blk) = global (row, blk^(row&7)).
// ---------------------------------------------------------------------------
__device__ __forceinline__ void stage_swz256(const ushort_t* __restrict__ g, int ldg,
                                             int rowBase, ushort_t* lds, int k0)
{
    const int tid = threadIdx.x;
    const int w = tid >> 6;
    #pragma unroll
    for (int u = 0; u < 4; ++u) {
        int e = tid * 8 + u * 2048;
        int row = e >> 6;
        int blk = (e >> 3) & 7;
        const ushort_t* src = g + (size_t)(rowBase + row) * ldg + k0 + ((blk ^ (row & 7)) << 3);
        ushort_t* dst = lds + w * 512 + u * 2048;
        gload_lds16(src, dst);
    }
}

// ---------------------------------------------------------------------------
// flash_attn v2: 256 thr = 4 waves, each wave 64t x 32s. t-tile 64.
// Per s-tile(128): stage bd(LDS linear) + k(swz); acc_s = bd; acc_s += qu.k;
// online softmax (cross-wave stats in LDS); P->Sp (swz); acc_o += P@vT.
// grid (T/64=16, nb*H). LDS = 16+16+16+2 = 50 KB -> ~3 blocks/CU.
// ---------------------------------------------------------------------------
__global__ __launch_bounds__(256, 3)
void flash_attn(const ushort_t* __restrict__ qu, const ushort_t* __restrict__ kb,
                const ushort_t* __restrict__ vT, const ushort_t* __restrict__ bdS,
                ushort_t* __restrict__ ctx, int b0)
{
    __shared__ ushort_t Sb[128 * 64];    // k (per kh) / vT (per sh), swizzled
    __shared__ ushort_t Sp[64 * 128];    // P bf16, row-swizzled
    __shared__ ushort_t Sd[64 * 128];    // bd tile, linear
    __shared__ float stats_m[4][64];
    __shared__ float stats_l[4][64];

    const int tid = threadIdx.x;
    const int lane = tid & 63, w = tid >> 6;
    const int wc = w * 32;
    const int lr = lane & 15;
    const int lg = lane >> 4;
    const int lrow4 = lg * 4;
    const int t0 = blockIdx.x * 64;
    const int lb = blockIdx.y >> 3, h = blockIdx.y & 7;
    const int b = b0 + lb;

    const ushort_t* quB = qu + (size_t)b * T_ * D_ + h * DK_;
    const ushort_t* kB  = kb + (size_t)b * T_ * D_ + h * DK_;
    const ushort_t* vTB = vT + (size_t)(b * H_ + h) * DK_ * T_;
    const ushort_t* bdB = bdS + (size_t)(lb * H_ + h) * T_ * T_;

    f32x4 acc_o[4][2];
    float m_run[4][4], l_run[4][4];
    #pragma unroll
    for (int i = 0; i < 4; ++i) {
        #pragma unroll
        for (int j = 0; j < 2; ++j)
            #pragma unroll
            for (int r = 0; r < 4; ++r) acc_o[i][j][r] = 0.f;
        #pragma unroll
        for (int r = 0; r < 4; ++r) { m_run[i][r] = -3.0e38f; l_run[i][r] = 0.f; }
    }

    for (int s0 = 0; s0 < T_; s0 += 128) {
        __syncthreads();                         // Sb/Sp/Sd free from prev iter
        // stage bd tile [64][128] linear (coalesced 16B/lane)
        #pragma unroll
        for (int u = 0; u < 4; ++u) {
            int e = tid * 8 + u * 2048;
            int row = e >> 7, col = e & 127;
            gload_lds16(bdB + (size_t)(t0 + row) * T_ + s0 + col, Sd + w * 512 + u * 2048);
        }
        stage_swz256(kB, D_, s0, Sb, 0);         // k K-half 0
        __syncthreads();

        // acc_s init from Sd (mask already folded into bdS)
        f32x4 acc_s[4][2];
        #pragma unroll
        for (int i = 0; i < 4; ++i)
            #pragma unroll
            for (int j = 0; j < 2; ++j)
                #pragma unroll
                for (int r = 0; r < 4; ++r)
                    acc_s[i][j][r] = bf2f(Sd[(i * 16 + lrow4 + r) * 128 + wc + j * 16 + lr]);

        // scores: acc_s += qu . k
        #pragma unroll
        for (int kh = 0; kh < 2; ++kh) {
            if (kh) {
                __syncthreads();
                stage_swz256(kB, D_, s0, Sb, 64);
                __syncthreads();
            }
            short8 aQ[2][4];
            #pragma unroll
            for (int kk = 0; kk < 2; ++kk)
                #pragma unroll
                for (int i = 0; i < 4; ++i)
                    aQ[kk][i] = *(const short8*)&quB[(size_t)(t0 + i * 16 + lr) * D_
                                                     + kh * 64 + kk * 32 + lg * 8];
            #pragma unroll
            for (int kk = 0; kk < 2; ++kk) {
                short8 bf[2];
                #pragma unroll
                for (int j = 0; j < 2; ++j) {
                    int row = wc + j * 16 + lr;
                    bf[j] = *(const short8*)&Sb[row * 64 + (((kk * 4 + lg) ^ (row & 7)) << 3)];
                }
                #pragma unroll
                for (int i = 0; i < 4; ++i)
                    #pragma unroll
                    for (int j = 0; j < 2; ++j)
                        acc_s[i][j] = __builtin_amdgcn_mfma_f32_16x16x32_bf16(
                            aQ[kk][i], bf[j], acc_s[i][j], 0, 0, 0);
            }
        }

        // online softmax
        #pragma unroll
        for (int i = 0; i < 4; ++i)
            #pragma unroll
            for (int r = 0; r < 4; ++r) {
                float mv = -3.0e38f;
                #pragma unroll
                for (int j = 0; j < 2; ++j) {
                    float sv = acc_s[i][j][r] * SCALE_F;
                    acc_s[i][j][r] = sv;
                    mv = fmaxf(mv, sv);
                }
                #pragma unroll
                for (int off = 1; off < 16; off <<= 1)
                    mv = fmaxf(mv, __shfl_xor(mv, off));
                if (lr == 0) stats_m[w][i * 16 + lrow4 + r] = mv;
            }
        __syncthreads();                         // stats_m ready; all waves past k-mma
        stage_swz256(vTB, T_, 0, Sb, s0);        // vT s-half 0 (overlaps softmax VALU)
        float fsc[4][4];
        #pragma unroll
        for (int i = 0; i < 4; ++i)
            #pragma unroll
            for (int r = 0; r < 4; ++r) {
                int row = i * 16 + lrow4 + r;
                float mt = fmaxf(fmaxf(stats_m[0][row], stats_m[1][row]),
                                 fmaxf(stats_m[2][row], stats_m[3][row]));
                float mn = fmaxf(m_run[i][r], mt);
                fsc[i][r] = __expf(m_run[i][r] - mn);
                m_run[i][r] = mn;
            }
        #pragma unroll
        for (int i = 0; i < 4; ++i)
            #pragma unroll
            for (int r = 0; r < 4; ++r) {
                float sum = 0.f;
                int row = i * 16 + lrow4 + r;
                #pragma unroll
                for (int j = 0; j < 2; ++j) {
                    float pexp = __expf(acc_s[i][j][r] - m_run[i][r]);
                    sum += pexp;
                    int c = wc + j * 16 + lr;
                    Sp[row * 128 + ((((c >> 3) ^ (row & 7)) << 3) | (c & 7))] = f2bf(pexp);
                }
                #pragma unroll
                for (int off = 1; off < 16; off <<= 1)
                    sum += __shfl_xor(sum, off);
                if (lr == 0) stats_l[w][row] = sum;
            }
        __syncthreads();                         // stats_l + Sp + SbV0 ready
        #pragma unroll
        for (int i = 0; i < 4; ++i)
            #pragma unroll
            for (int r = 0; r < 4; ++r) {
                int row = i * 16 + lrow4 + r;
                l_run[i][r] = l_run[i][r] * fsc[i][r]
                            + stats_l[0][row] + stats_l[1][row]
                            + stats_l[2][row] + stats_l[3][row];
            }
        #pragma unroll
        for (int i = 0; i < 4; ++i)
            #pragma unroll
            for (int j = 0; j < 2; ++j)
                #pragma unroll
                for (int r = 0; r < 4; ++r)
                    acc_o[i][j][r] *= fsc[i][r];

        // PV: acc_o += P @ vT
        #pragma unroll
        for (int sh = 0; sh < 2; ++sh) {
            if (sh) {
                __syncthreads();
                stage_swz256(vTB, T_, 0, Sb, s0 + 64);
                __syncthreads();
            }
            #pragma unroll
            for (int kk = 0; kk < 2; ++kk) {
                short8 bf[2], af[4];
                #pragma unroll
                for (int j = 0; j < 2; ++j) {
                    int row = wc + j * 16 + lr;
                    bf[j] = *(const short8*)&Sb[row * 64 + (((kk * 4 + lg) ^ (row & 7)) << 3)];
                }
                #pragma unroll
                for (int i = 0; i < 4; ++i) {
                    int rowA = i * 16 + lr;
                    int cb = sh * 8 + kk * 4 + lg;
                    af[i] = *(const short8*)&Sp[rowA * 128 + ((cb ^ (rowA & 7)) << 3)];
                }
                #pragma unroll
                for (int i = 0; i < 4; ++i)
                    #pragma unroll
                    for (int j = 0; j < 2; ++j)
                        acc_o[i][j] = __builtin_amdgcn_mfma_f32_16x16x32_bf16(
                            af[i], bf[j], acc_o[i][j], 0, 0, 0);
            }
        }
    }

    // epilogue: ctx = acc_o / l (0 if fully-masked row)
    #pragma unroll
    for (int i = 0; i < 4; ++i)
        #pragma unroll
        for (int r = 0; r < 4; ++r) {
            float inv = (m_run[i][r] < -5000.f) ? 0.f : 1.f / l_run[i][r];
            #pragma unroll
            for (int j = 0; j < 2; ++j) {
                int t = t0 + i * 16 + lrow4 + r;
                int n = wc + j * 16 + lr;
                ctx[((size_t)(b * T_ + t)) * D_ + h * DK_ + n] = f2bf(acc_o[i][j][r] * inv);
            }
        }
}

// ---------------------------------------------------------------------------
// casts / transposes
// ---------------------------------------------------------------------------
__global__ __launch_bounds__(256)
void cast_bf16(const float* __restrict__ in, ushort_t* __restrict__ out, int n)
{
    int i = (blockIdx.x * 256 + threadIdx.x) * 8;
    if (i >= n) return;
    float4 a = *(const float4*)&in[i];
    float4 bq = *(const float4*)&in[i + 4];
    ushortx8 r;
    r[0] = f2bf(a.x); r[1] = f2bf(a.y); r[2] = f2bf(a.z); r[3] = f2bf(a.w);
    r[4] = f2bf(bq.x); r[5] = f2bf(bq.y); r[6] = f2bf(bq.z); r[7] = f2bf(bq.w);
    *(ushortx8*)&out[i] = r;
}

__global__ __launch_bounds__(256)
void wt_cast(const float* __restrict__ W, ushort_t* __restrict__ Wt)
{
    __shared__ float tile[32][33];
    const int n0 = blockIdx.x * 32, k0 = blockIdx.y * 32;
    const int lx = threadIdx.x & 31, ly = threadIdx.x >> 5;
    #pragma unroll
    for (int r = 0; r < 32; r += 8)
        tile[ly + r][lx] = W[(size_t)(k0 + ly + r) * 1024 + n0 + lx];
    __syncthreads();
    #pragma unroll
    for (int r = 0; r < 32; r += 8)
        Wt[(size_t)(n0 + ly + r) * 1024 + k0 + lx] = f2bf(tile[lx][ly + r]);
}

__global__ __launch_bounds__(256)
void vt_trans(const ushort_t* __restrict__ v, ushort_t* __restrict__ vT)
{
    __shared__ ushort_t tile[32][33];
    const int t0 = blockIdx.x * 32, n0 = blockIdx.y * 32;
    const int bh = blockIdx.z;
    const int b = bh >> 3, h = bh & 7;
    const int lx = threadIdx.x & 31, ly = threadIdx.x >> 5;
    const ushort_t* src = v + (size_t)b * T_ * D_ + h * DK_;
    #pragma unroll
    for (int r = 0; r < 32; r += 8)
        tile[ly + r][lx] = src[(size_t)(t0 + ly + r) * D_ + n0 + lx];
    __syncthreads();
    ushort_t* dst = vT + (size_t)bh * DK_ * T_;
    #pragma unroll
    for (int r = 0; r < 32; r += 8)
        dst[(size_t)(n0 + ly + r) * T_ + t0 + lx] = tile[lx][ly + r];
}

// ---------------------------------------------------------------------------
extern "C" void kernel_launch(void* const* d_in, const int* in_sizes, int n_in,
                              void* d_out, int out_size, void* d_ws, size_t ws_size,
                              hipStream_t stream)
{
    const float* query   = (const float*)d_in[0];
    const float* key     = (const float*)d_in[1];
    const float* value   = (const float*)d_in[2];
    const float* pos_emb = (const float*)d_in[3];
    const unsigned char* mask = (const unsigned char*)d_in[4];
    const float* Wq  = (const float*)d_in[5];
    const float* bq  = (const float*)d_in[6];
    const float* Wk  = (const float*)d_in[7];
    const float* bk  = (const float*)d_in[8];
    const float* Wv  = (const float*)d_in[9];
    const float* bv  = (const float*)d_in[10];
    const float* Wp  = (const float*)d_in[11];
    const float* Wo  = (const float*)d_in[12];
    const float* bo  = (const float*)d_in[13];
    const float* pbu = (const float*)d_in[14];
    const float* pbv = (const float*)d_in[15];
    float* out = (float*)d_out;

    const size_t SZ_BTD = (size_t)B_ * T_ * D_;       // 4,194,304
    const size_t SZ_PD  = (size_t)P_ * D_;            // 2,096,128
    const size_t SZ_W   = (size_t)D_ * D_;            // 1,048,576

    ushort_t* c = (ushort_t*)d_ws;
    ushort_t* qbf  = c; c += SZ_BTD;
    ushort_t* kbfi = c; c += SZ_BTD;
    ushort_t* vbfi = c; c += SZ_BTD;
    ushort_t* pbf  = c; c += SZ_PD;
    ushort_t* WqT = c; c += SZ_W;
    ushort_t* WkT = c; c += SZ_W;
    ushort_t* WvT = c; c += SZ_W;
    ushort_t* WpT = c; c += SZ_W;
    ushort_t* WoT = c; c += SZ_W;
    ushort_t* qu  = c; c += SZ_BTD;
    ushort_t* qv  = c; c += SZ_BTD;
    ushort_t* kb  = c; c += SZ_BTD;
    ushort_t* vb  = c; c += SZ_BTD;
    ushort_t* ctx = c; c += SZ_BTD;
    ushort_t* vT  = c; c += SZ_BTD;
    ushort_t* pp  = c; c += SZ_PD;

    const size_t base_bytes = (size_t)((char*)c - (char*)d_ws);
    const size_t per_b = (size_t)H_ * T_ * T_ * 2;    // bdS bf16 per batch
    int SB = 1;
    if (ws_size > base_bytes) {
        size_t sb = (ws_size - base_bytes) / per_b;
        SB = sb < 1 ? 1 : (sb > B_ ? B_ : (int)sb);
    }
    ushort_t* bdS = c;

    // casts
    cast_bf16<<<dim3((int)(SZ_BTD / 8 / 256)), 256, 0, stream>>>(query, qbf, (int)SZ_BTD);
    cast_bf16<<<dim3((int)(SZ_BTD / 8 / 256)), 256, 0, stream>>>(key, kbfi, (int)SZ_BTD);
    cast_bf16<<<dim3((int)(SZ_BTD / 8 / 256)), 256, 0, stream>>>(value, vbfi, (int)SZ_BTD);
    cast_bf16<<<dim3((int)((SZ_PD / 8 + 255) / 256)), 256, 0, stream>>>(pos_emb, pbf, (int)SZ_PD);
    wt_cast<<<dim3(32, 32), 256, 0, stream>>>(Wq, WqT);
    wt_cast<<<dim3(32, 32), 256, 0, stream>>>(Wk, WkT);
    wt_cast<<<dim3(32, 32), 256, 0, stream>>>(Wv, WvT);
    wt_cast<<<dim3(32, 32), 256, 0, stream>>>(Wp, WpT);
    wt_cast<<<dim3(32, 32), 256, 0, stream>>>(Wo, WoT);

    // combined projections (q dual, k, v, p)
    gemm_qkvp<<<dim3(8, 32, 4), 256, 0, stream>>>(qbf, kbfi, vbfi, pbf,
                                                  WqT, WkT, WvT, WpT,
                                                  bq, bk, bv,
                                                  qu, qv, kb, vb, pp, pbu, pbv);
    vt_trans<<<dim3(32, 4, 32), 256, 0, stream>>>(vb, vT);

    // attention, chunked over batch
    for (int b0 = 0; b0 < B_; b0 += SB) {
        int nb = B_ - b0; if (nb > SB) nb = SB;
        gemm_bd_shifted<<<dim3(16, 8, nb * H_), 256, 0, stream>>>(qv, pp, mask, bdS, b0);
        flash_attn     <<<dim3(16, nb * H_),    256, 0, stream>>>(qu, kb, vT, bdS, ctx, b0);
    }

    // output projection (fp32 out)
    gemm_out<<<dim3(8, 32), 256, 0, stream>>>(ctx, WoT, bo, out, B_ * T_);
}